// Round 2
// baseline (324.600 us; speedup 1.0000x reference)
//
#include <hip/hip_runtime.h>
#include <hip/hip_bf16.h>

#define BATCH 16
#define HH    48
#define WW    64
#define CC    256
#define ND    21          // displacements per axis
#define OUTD  441         // 21*21
#define PITCH 264         // LDS row pitch in bf16 elems: 16B-aligned rows
#define SROWS 32          // per-parity staged rows: srow = j>>1, j in [0,64)

typedef __bf16 v8bf16 __attribute__((ext_vector_type(8)));
typedef float  v4f    __attribute__((ext_vector_type(4)));

// out[b,h,w, tj*21+ti] = (1/256) * sum_c A[b,h,w,c] * Bpad[b, h+2tj-20, w+2ti-20, c]
// Parity split: w = 2w'+p, j = w+2ti-20 = 2(w'+ti-10)+p.
// Only in-image j in [0,64) is computed (s = (j>>1)+10 in [10,42) = 2 MFMA tiles);
// out-of-image j => output is exactly 0 (B is zero-pad there) => written directly.
__global__ __launch_bounds__(256, 4)
void corr_mfma_kernel(const float* __restrict__ A, const float* __restrict__ B,
                      float* __restrict__ out) {
    __shared__ __bf16 Blds[2 * SROWS * PITCH];   // 33,792 B -> 4 blocks/CU

    const int bh   = blockIdx.x;
    const int b    = bh / HH;
    const int h    = bh % HH;
    const int tid  = threadIdx.x;
    const int lane = tid & 63;
    const int wave = tid >> 6;
    const int p    = wave & 1;    // parity of w
    const int mt   = wave >> 1;   // w'-tile: w' in [16*mt, 16*mt+16)
    const int n    = lane & 15;
    const int quad = lane >> 4;

    float* outbh = out + (size_t)bh * WW * OUTD;

    // valid tj range: hb = h + 2*tj - 20 in [0,48)
    const int tj_lo = (h >= 20) ? 0 : ((21 - h) >> 1);
    const int tj_hi = min(20, (67 - h) >> 1);

    // zero-fill outputs for invalid tj (B row fully out of range)
    for (int tj = 0; tj < ND; ++tj) {
        if (tj >= tj_lo && tj <= tj_hi) continue;
        for (int idx = tid; idx < WW * ND; idx += 256) {
            int w = idx / ND, ti = idx - w * ND;
            outbh[(size_t)w * OUTD + tj * ND + ti] = 0.f;
        }
    }

    // Preload A fragments (tj-invariant): lane holds A_p[16mt+n][kc*32 + quad*8 .. +7]
    v8bf16 afrag[8];
    {
        int w_a = ((mt * 16 + n) << 1) + p;
        const float* arow = A + ((size_t)(b * HH + h) * WW + w_a) * CC;
        #pragma unroll
        for (int kc = 0; kc < 8; ++kc) {
            int c0 = kc * 32 + quad * 8;
            float4 f0 = *(const float4*)(arow + c0);
            float4 f1 = *(const float4*)(arow + c0 + 4);
            v8bf16 af;
            af[0] = (__bf16)f0.x; af[1] = (__bf16)f0.y; af[2] = (__bf16)f0.z; af[3] = (__bf16)f0.w;
            af[4] = (__bf16)f1.x; af[5] = (__bf16)f1.y; af[6] = (__bf16)f1.z; af[7] = (__bf16)f1.w;
            afrag[kc] = af;
        }
    }

    // staging constants: wave stages global rows w = wave + 4*it
    //   parity pp = wave&1 (4*it is even), srow = (w>>1) = (wave>>1) + 2*it
    const int pp     = wave & 1;
    const int srow_w = wave >> 1;
    const int c4     = lane << 2;

    for (int tj = tj_lo; tj <= tj_hi; ++tj) {
        const int hb = h + 2 * tj - 20;
        __syncthreads();   // previous compute done before overwriting Blds

        const float* brow = B + (size_t)(b * HH + hb) * WW * CC;
        #pragma unroll
        for (int it = 0; it < 16; ++it) {
            int w = wave + 4 * it;
            float4 f = *(const float4*)(brow + (size_t)w * CC + c4);
            __bf16* dst = &Blds[(pp * SROWS + srow_w + 2 * it) * PITCH + c4];
            dst[0] = (__bf16)f.x; dst[1] = (__bf16)f.y;
            dst[2] = (__bf16)f.z; dst[3] = (__bf16)f.w;
        }
        __syncthreads();

        v4f acc0 = {0.f, 0.f, 0.f, 0.f};
        v4f acc1 = acc0;
        const __bf16* bbase = &Blds[(p * SROWS + n) * PITCH + quad * 8];
        #pragma unroll
        for (int kc = 0; kc < 8; ++kc) {
            int ko = kc * 32;
            v8bf16 b0 = *(const v8bf16*)(bbase + ko);                // s = 10 + n
            v8bf16 b1 = *(const v8bf16*)(bbase + 16 * PITCH + ko);   // s = 26 + n
            acc0 = __builtin_amdgcn_mfma_f32_16x16x32_bf16(afrag[kc], b0, acc0, 0, 0, 0);
            acc1 = __builtin_amdgcn_mfma_f32_16x16x32_bf16(afrag[kc], b1, acc1, 0, 0, 0);
        }

        // epilogue: D layout col = lane&15 (-> s index n), row = quad*4 + r (-> w' in tile)
        #pragma unroll
        for (int r = 0; r < 4; ++r) {
            int wp = mt * 16 + quad * 4 + r;     // w'
            int w  = (wp << 1) + p;
            float* orow = outbh + (size_t)w * OUTD + tj * ND;
            int ti0 = 10 + n - wp;               // tile0: s = 10 + n
            if ((unsigned)ti0 < 21u) orow[ti0] = acc0[r] * (1.f / 256.f);
            int ti1 = 26 + n - wp;               // tile1: s = 26 + n
            if ((unsigned)ti1 < 21u) orow[ti1] = acc1[r] * (1.f / 256.f);
            // out-of-image j => exact zeros: ti in [0, 10-wp) and [42-wp, 21)
            if (n < 10 - wp)  orow[n]      = 0.f;
            if (n <= wp - 22) orow[20 - n] = 0.f;
        }
    }
}

extern "C" void kernel_launch(void* const* d_in, const int* in_sizes, int n_in,
                              void* d_out, int out_size, void* d_ws, size_t ws_size,
                              hipStream_t stream) {
    const float* A = (const float*)d_in[0];
    const float* B = (const float*)d_in[1];
    float* out = (float*)d_out;
    dim3 grid(BATCH * HH);
    dim3 block(256);
    corr_mfma_kernel<<<grid, block, 0, stream>>>(A, B, out);
}

// Round 3
// 293.884 us; speedup vs baseline: 1.1045x; 1.1045x over previous
//
#include <hip/hip_runtime.h>
#include <hip/hip_bf16.h>

#define BATCH 16
#define HH    48
#define WW    64
#define CC    256
#define ND    21          // displacements per axis
#define OUTD  441         // 21*21
#define PITCH 264         // LDS row pitch in bf16 elems: 16B-aligned rows
#define SROWS 32          // per-parity staged rows: srow = j>>1, j in [0,64)

typedef __bf16 v8bf16 __attribute__((ext_vector_type(8)));
typedef float  v4f    __attribute__((ext_vector_type(4)));

// out[b,h,w, tj*21+ti] = (1/256) * sum_c A[b,h,w,c] * Bpad[b, h+2tj-20, w+2ti-20, c]
// Block owns (b, hb): stages B[b,hb] in LDS ONCE, then loops (barrier-free) over
// the <=21 output rows h that correlate against hb (h == hb mod 2, |h-hb| <= 20,
// tj = (20 + hb - h)/2), loading A fragments straight from global into registers.
__global__ __launch_bounds__(256)
void corr_mfma_kernel(const float* __restrict__ A, const float* __restrict__ B,
                      float* __restrict__ out) {
    __shared__ __bf16 Blds[2 * SROWS * PITCH];   // 33,792 B

    const int bhb  = blockIdx.x;
    const int b    = bhb / HH;
    const int hb   = bhb % HH;
    const int tid  = threadIdx.x;
    const int lane = tid & 63;
    const int wave = tid >> 6;
    const int p    = wave & 1;    // parity of w
    const int mt   = wave >> 1;   // w'-tile: w' in [16*mt, 16*mt+16)
    const int n    = lane & 15;
    const int quad = lane >> 4;

    // ---- stage B row hb -> LDS (once) ----
    {
        const float* brow = B + (size_t)(b * HH + hb) * WW * CC;
        const int pp     = wave & 1;     // w = wave + 4*it: parity = wave&1
        const int srow_w = wave >> 1;
        const int c4     = lane << 2;
        #pragma unroll
        for (int it = 0; it < 16; ++it) {
            int w = wave + 4 * it;
            float4 f = *(const float4*)(brow + (size_t)w * CC + c4);
            __bf16* dst = &Blds[(pp * SROWS + srow_w + 2 * it) * PITCH + c4];
            dst[0] = (__bf16)f.x; dst[1] = (__bf16)f.y;
            dst[2] = (__bf16)f.z; dst[3] = (__bf16)f.w;
        }
    }

    // ---- zero-fill invalid-tj entries of output row h = hb ----
    {
        float* outbh = out + (size_t)(b * HH + hb) * WW * OUTD;
        const int tj_lo = (hb >= 20) ? 0 : ((21 - hb) >> 1);
        const int tj_hi = min(20, (67 - hb) >> 1);
        for (int tj = 0; tj < ND; ++tj) {
            if (tj >= tj_lo && tj <= tj_hi) continue;
            for (int idx = tid; idx < WW * ND; idx += 256) {
                int w = idx / ND, ti = idx - w * ND;
                outbh[(size_t)w * OUTD + tj * ND + ti] = 0.f;
            }
        }
    }

    __syncthreads();   // the only barrier

    const __bf16* bbase = &Blds[(p * SROWS + n) * PITCH + quad * 8];

    // valid h-iterations: h = hb - 20 + 2k, k in [k_lo, k_hi]; tj = 20 - k
    const int k_lo = (hb >= 20) ? 0 : ((21 - hb) >> 1);
    const int k_hi = min(20, (67 - hb) >> 1);
    const int w_a  = ((mt * 16 + n) << 1) + p;

    for (int k = k_lo; k <= k_hi; ++k) {
        const int h  = hb - 20 + 2 * k;
        const int tj = 20 - k;

        // A fragments straight from global (no LDS, no barrier)
        const float* arow = A + ((size_t)(b * HH + h) * WW + w_a) * CC;
        v8bf16 afrag[8];
        #pragma unroll
        for (int kc = 0; kc < 8; ++kc) {
            int c0 = kc * 32 + quad * 8;
            float4 f0 = *(const float4*)(arow + c0);
            float4 f1 = *(const float4*)(arow + c0 + 4);
            v8bf16 af;
            af[0] = (__bf16)f0.x; af[1] = (__bf16)f0.y; af[2] = (__bf16)f0.z; af[3] = (__bf16)f0.w;
            af[4] = (__bf16)f1.x; af[5] = (__bf16)f1.y; af[6] = (__bf16)f1.z; af[7] = (__bf16)f1.w;
            afrag[kc] = af;
        }

        v4f acc0 = {0.f, 0.f, 0.f, 0.f};
        v4f acc1 = acc0;
        #pragma unroll
        for (int kc = 0; kc < 8; ++kc) {
            int ko = kc * 32;
            v8bf16 b0 = *(const v8bf16*)(bbase + ko);                // j' = n
            v8bf16 b1 = *(const v8bf16*)(bbase + 16 * PITCH + ko);   // j' = 16 + n
            acc0 = __builtin_amdgcn_mfma_f32_16x16x32_bf16(afrag[kc], b0, acc0, 0, 0, 0);
            acc1 = __builtin_amdgcn_mfma_f32_16x16x32_bf16(afrag[kc], b1, acc1, 0, 0, 0);
        }

        // epilogue: D layout col = lane&15 (-> j' index n), row = quad*4 + r (-> w')
        float* outr = out + (size_t)(b * HH + h) * WW * OUTD;
        #pragma unroll
        for (int r = 0; r < 4; ++r) {
            int wp = mt * 16 + quad * 4 + r;     // w'
            int w  = (wp << 1) + p;
            float* orow = outr + (size_t)w * OUTD + tj * ND;
            int ti0 = 10 + n - wp;               // tile0: j' = n
            if ((unsigned)ti0 < 21u) orow[ti0] = acc0[r] * (1.f / 256.f);
            int ti1 = 26 + n - wp;               // tile1: j' = 16 + n
            if ((unsigned)ti1 < 21u) orow[ti1] = acc1[r] * (1.f / 256.f);
            // out-of-image j => exact zeros
            if (n < 10 - wp)  orow[n]      = 0.f;
            if (n <= wp - 22) orow[20 - n] = 0.f;
        }
    }
}

extern "C" void kernel_launch(void* const* d_in, const int* in_sizes, int n_in,
                              void* d_out, int out_size, void* d_ws, size_t ws_size,
                              hipStream_t stream) {
    const float* A = (const float*)d_in[0];
    const float* B = (const float*)d_in[1];
    float* out = (float*)d_out;
    dim3 grid(BATCH * HH);
    dim3 block(256);
    corr_mfma_kernel<<<grid, block, 0, stream>>>(A, B, out);
}

// Round 4
// 209.882 us; speedup vs baseline: 1.5466x; 1.4002x over previous
//
#include <hip/hip_runtime.h>
#include <hip/hip_bf16.h>

#define HH    48
#define WW    64
#define CC    256
#define ND    21
#define OUTD  441
#define PITCH 264        // LDS row pitch in bf16 elems (16B-aligned rows, 4-bank rotate)
#define SROWS 32         // j' rows per parity

typedef __bf16 v8bf16 __attribute__((ext_vector_type(8)));
typedef float  v4f    __attribute__((ext_vector_type(4)));

// out[b,h,w, tj*21+ti] = (1/256) * sum_c A[b,h,w,c] * Bpad[b, h+2tj-20, w+2ti-20, c]
// h-parity and w-parity both decompose the problem. Block owns (b, w-parity p,
// h-triple {h0,h0+2,h0+4}): A fragments in registers (1 h-row per wave, loaded once),
// loop over shared hb rows; stage B[hb] parity-p cols to LDS (double-buffered,
// register-prefetched, one barrier/iter). Each staged row serves up to 3 (h,tj) pairs.
__global__ __launch_bounds__(384)
void corr_mfma_kernel(const float* __restrict__ A, const float* __restrict__ B,
                      float* __restrict__ out) {
    __shared__ __bf16 Blds[2][SROWS * PITCH];   // 2 x 16,896 B

    const int blk  = blockIdx.x;
    const int b    = blk >> 5;        // 16 images
    const int rem  = blk & 31;        // 32 blocks/image
    const int p    = rem & 1;         // w parity
    const int hpar = (rem >> 1) & 1;  // h parity
    const int trip = rem >> 2;        // [0,8)
    const int h0   = 6 * trip + hpar; // rows h0, h0+2, h0+4

    const int tid  = threadIdx.x;
    const int lane = tid & 63;
    const int wave = tid >> 6;        // [0,6)
    const int mt   = wave & 1;        // w'-tile
    const int hr   = wave >> 1;       // [0,3): which h-row
    const int n    = lane & 15;
    const int quad = lane >> 4;

    const int h = h0 + 2 * hr;

    // hb = h0 - 20 + 2i ; i range keeping hb in [0,48)
    const int i_lo = (h0 >= 21) ? 0 : ((21 - h0) >> 1);
    const int i_hi = min(22, (67 - h0) >> 1);

    // ---- zero-fill invalid-tj entries for the 3 rows (parity-p w columns only) ----
    for (int r = 0; r < 3; ++r) {
        int hrow  = h0 + 2 * r;
        int tv_lo = max(0, i_lo - r);
        int tv_hi = min(20, i_hi - r);
        float* outr = out + (size_t)(b * HH + hrow) * WW * OUTD;
        for (int tj = 0; tj < ND; ++tj) {
            if (tj >= tv_lo && tj <= tv_hi) continue;
            for (int idx = tid; idx < 32 * ND; idx += 384) {
                int wp = idx / ND, ti = idx - wp * ND;
                int w  = (wp << 1) + p;
                outr[(size_t)w * OUTD + tj * ND + ti] = 0.f;
            }
        }
    }

    // ---- A fragments (loop-invariant, loaded once) ----
    v8bf16 afrag[8];
    {
        int w_a = ((mt * 16 + n) << 1) + p;
        const float* arow = A + ((size_t)(b * HH + h) * WW + w_a) * CC;
        #pragma unroll
        for (int kc = 0; kc < 8; ++kc) {
            int c0 = kc * 32 + quad * 8;
            float4 f0 = *(const float4*)(arow + c0);
            float4 f1 = *(const float4*)(arow + c0 + 4);
            v8bf16 af;
            af[0] = (__bf16)f0.x; af[1] = (__bf16)f0.y; af[2] = (__bf16)f0.z; af[3] = (__bf16)f0.w;
            af[4] = (__bf16)f1.x; af[5] = (__bf16)f1.y; af[6] = (__bf16)f1.z; af[7] = (__bf16)f1.w;
            afrag[kc] = af;
        }
    }

    // ---- staging: 32 j'-rows x 64 float4-chunks = 2048 chunks over 384 threads ----
    const float* bimg = B + (size_t)(b * HH) * WW * CC + p * CC;  // +p: j = 2j'+p
    float4 pf[6];
    auto load_pf = [&](int hb) {
        const float* brow = bimg + (size_t)hb * WW * CC;
        #pragma unroll
        for (int it = 0; it < 6; ++it) {
            int idx = it * 384 + tid;
            if (idx < 2048)
                pf[it] = *(const float4*)(brow + (idx >> 6) * 2 * CC + ((idx & 63) << 2));
        }
    };
    auto store_lds = [&](int buf) {
        #pragma unroll
        for (int it = 0; it < 6; ++it) {
            int idx = it * 384 + tid;
            if (idx < 2048) {
                __bf16* dst = &Blds[buf][(idx >> 6) * PITCH + ((idx & 63) << 2)];
                dst[0] = (__bf16)pf[it].x; dst[1] = (__bf16)pf[it].y;
                dst[2] = (__bf16)pf[it].z; dst[3] = (__bf16)pf[it].w;
            }
        }
    };

    load_pf(h0 - 20 + 2 * i_lo);
    store_lds(0);
    int cur = 0;

    float* outr = out + (size_t)(b * HH + h) * WW * OUTD;

    for (int i = i_lo; i <= i_hi; ++i) {
        if (i < i_hi) load_pf(h0 - 20 + 2 * (i + 1));   // prefetch next hb (in flight)
        __syncthreads();   // buf[cur] writes visible; prior readers of buf[cur^1] done

        const int tj = i - hr;
        if ((unsigned)tj <= 20u) {
            const __bf16* bbase = &Blds[cur][n * PITCH + quad * 8];
            v4f acc0 = {0.f, 0.f, 0.f, 0.f};
            v4f acc1 = acc0;
            #pragma unroll
            for (int kc = 0; kc < 8; ++kc) {
                v8bf16 bf0 = *(const v8bf16*)(bbase + kc * 32);                // j' = n
                v8bf16 bf1 = *(const v8bf16*)(bbase + 16 * PITCH + kc * 32);   // j' = 16+n
                acc0 = __builtin_amdgcn_mfma_f32_16x16x32_bf16(afrag[kc], bf0, acc0, 0, 0, 0);
                acc1 = __builtin_amdgcn_mfma_f32_16x16x32_bf16(afrag[kc], bf1, acc1, 0, 0, 0);
            }
            // epilogue: D col = n (-> j'), row = quad*4 + r (-> w' within tile)
            #pragma unroll
            for (int r = 0; r < 4; ++r) {
                int wp = mt * 16 + quad * 4 + r;
                int w  = (wp << 1) + p;
                float* orow = outr + (size_t)w * OUTD + tj * ND;
                int ti0 = 10 + n - wp;
                if ((unsigned)ti0 < 21u) orow[ti0] = acc0[r] * (1.f / 256.f);
                int ti1 = 26 + n - wp;
                if ((unsigned)ti1 < 21u) orow[ti1] = acc1[r] * (1.f / 256.f);
                // out-of-image j => exact zeros
                if (n < 10 - wp)  orow[n]      = 0.f;
                if (n <= wp - 22) orow[20 - n] = 0.f;
            }
        }

        if (i < i_hi) store_lds(cur ^ 1);   // consume pf; other buffer, no race
        cur ^= 1;
    }
}

extern "C" void kernel_launch(void* const* d_in, const int* in_sizes, int n_in,
                              void* d_out, int out_size, void* d_ws, size_t ws_size,
                              hipStream_t stream) {
    const float* A = (const float*)d_in[0];
    const float* B = (const float*)d_in[1];
    float* out = (float*)d_out;
    dim3 grid(16 * 32);
    dim3 block(384);
    corr_mfma_kernel<<<grid, block, 0, stream>>>(A, B, out);
}